// Round 2
// baseline (1590.647 us; speedup 1.0000x reference)
//
#include <hip/hip_runtime.h>
#include <hip/hip_bf16.h>
#include <cstdint>

#define NN 50000
#define TT 8
#define DD 256
#define HH 128
#define EE 800000
#define GG 4

// ---------------- attention + projection (fused, G nodes per block) ----------------
__global__ __launch_bounds__(256) void k_att(
    const float* __restrict__ x,
    const float* __restrict__ Wac, const float* __restrict__ bac, const float* __restrict__ vac,
    const float* __restrict__ Wao, const float* __restrict__ bao, const float* __restrict__ vao,
    const float* __restrict__ Wc, const float* __restrict__ Wo,
    float* __restrict__ cp, float* __restrict__ op)
{
    __shared__ float xs[GG * TT * DD];        // 32 KB
    __shared__ float e_lds[2][GG][TT];        // 256 B
    __shared__ float pooled[2][GG][DD];       // 8 KB
    const int tid = threadIdx.x;
    const int n0 = blockIdx.x * GG;

    // stage x[n0..n0+3] into LDS (contiguous copy, float4)
    {
        const float4* xg = (const float4*)(x + (size_t)n0 * (TT * DD));
        float4* xl = (float4*)xs;
        #pragma unroll
        for (int k = 0; k < 8; ++k) xl[k * 256 + tid] = xg[k * 256 + tid];
    }
    __syncthreads();

    // ---- h = tanh(xW+b), e = h.v : thread = (t, 4 features) ----
    const int t = tid >> 5;     // 0..7
    const int q = tid & 31;     // feature group: j = 4q..4q+3

    float4 ac[GG], ao[GG];
    #pragma unroll
    for (int g = 0; g < GG; ++g) {
        ac[g] = make_float4(0.f, 0.f, 0.f, 0.f);
        ao[g] = make_float4(0.f, 0.f, 0.f, 0.f);
    }

    const float4* wc4 = (const float4*)Wac;   // [D][32 float4]
    const float4* wo4 = (const float4*)Wao;
    for (int d = 0; d < DD; ++d) {
        float4 wc = wc4[d * 32 + q];
        float4 wo = wo4[d * 32 + q];
        #pragma unroll
        for (int g = 0; g < GG; ++g) {
            float xv = xs[(g * TT + t) * DD + d];
            ac[g].x = fmaf(xv, wc.x, ac[g].x);
            ac[g].y = fmaf(xv, wc.y, ac[g].y);
            ac[g].z = fmaf(xv, wc.z, ac[g].z);
            ac[g].w = fmaf(xv, wc.w, ac[g].w);
            ao[g].x = fmaf(xv, wo.x, ao[g].x);
            ao[g].y = fmaf(xv, wo.y, ao[g].y);
            ao[g].z = fmaf(xv, wo.z, ao[g].z);
            ao[g].w = fmaf(xv, wo.w, ao[g].w);
        }
    }

    {
        float4 bcv = ((const float4*)bac)[q];
        float4 vcv = ((const float4*)vac)[q];
        float4 bov = ((const float4*)bao)[q];
        float4 vov = ((const float4*)vao)[q];
        #pragma unroll
        for (int g = 0; g < GG; ++g) {
            float pc = tanhf(ac[g].x + bcv.x) * vcv.x + tanhf(ac[g].y + bcv.y) * vcv.y
                     + tanhf(ac[g].z + bcv.z) * vcv.z + tanhf(ac[g].w + bcv.w) * vcv.w;
            float po = tanhf(ao[g].x + bov.x) * vov.x + tanhf(ao[g].y + bov.y) * vov.y
                     + tanhf(ao[g].z + bov.z) * vov.z + tanhf(ao[g].w + bov.w) * vov.w;
            #pragma unroll
            for (int m = 16; m; m >>= 1) {
                pc += __shfl_xor(pc, m, 32);
                po += __shfl_xor(po, m, 32);
            }
            if (q == 0) { e_lds[0][g][t] = pc; e_lds[1][g][t] = po; }
        }
    }
    __syncthreads();

    // ---- softmax over T (redundant per thread) + pooled: thread owns feature d=tid ----
    {
        const int d = tid;
        #pragma unroll
        for (int g = 0; g < GG; ++g) {
            float ec[TT], eo[TT];
            float mc = -1e30f, mo = -1e30f;
            #pragma unroll
            for (int u = 0; u < TT; ++u) {
                ec[u] = e_lds[0][g][u]; mc = fmaxf(mc, ec[u]);
                eo[u] = e_lds[1][g][u]; mo = fmaxf(mo, eo[u]);
            }
            float sc = 0.f, so = 0.f;
            #pragma unroll
            for (int u = 0; u < TT; ++u) {
                ec[u] = __expf(ec[u] - mc); sc += ec[u];
                eo[u] = __expf(eo[u] - mo); so += eo[u];
            }
            float plc = 0.f, plo = 0.f;
            #pragma unroll
            for (int u = 0; u < TT; ++u) {
                float xv = xs[(g * TT + u) * DD + d];
                plc = fmaf(ec[u], xv, plc);
                plo = fmaf(eo[u], xv, plo);
            }
            pooled[0][g][d] = plc / sc;
            pooled[1][g][d] = plo / so;
        }
    }
    __syncthreads();

    // ---- projection: cp = pooled_c @ Wc, op = pooled_o @ Wo (bias added later) ----
    {
        const int j  = tid & 127;
        const int h2 = tid >> 7;                 // 0 = center head, 1 = offset head
        const float* W  = h2 ? Wo : Wc;
        const float* pl = &pooled[h2][0][0];
        float acc[GG] = {0.f, 0.f, 0.f, 0.f};
        for (int d2 = 0; d2 < DD; ++d2) {
            float w = W[d2 * HH + j];
            #pragma unroll
            for (int g = 0; g < GG; ++g) acc[g] = fmaf(pl[g * DD + d2], w, acc[g]);
        }
        float* o = h2 ? op : cp;
        #pragma unroll
        for (int g = 0; g < GG; ++g) o[(size_t)(n0 + g) * HH + j] = acc[g];
    }
}

// ---------------- CSR build ----------------
__global__ void k_count(const int* __restrict__ dst, int* __restrict__ counts) {
    int e = blockIdx.x * 256 + threadIdx.x;
    if (e < EE) atomicAdd(&counts[dst[e]], 1);
}

__global__ __launch_bounds__(1024) void k_scan(const int* __restrict__ counts, int* __restrict__ starts) {
    __shared__ int sdata[1024];
    __shared__ int s_running;
    if (threadIdx.x == 0) s_running = 0;
    __syncthreads();
    const int nChunks = (NN + 1023) / 1024;
    for (int c = 0; c < nChunks; ++c) {
        int i = c * 1024 + threadIdx.x;
        int v = (i < NN) ? counts[i] : 0;
        sdata[threadIdx.x] = v;
        __syncthreads();
        for (int off = 1; off < 1024; off <<= 1) {
            int tv = (threadIdx.x >= off) ? sdata[threadIdx.x - off] : 0;
            __syncthreads();
            sdata[threadIdx.x] += tv;
            __syncthreads();
        }
        int incl = sdata[threadIdx.x];
        int run = s_running;
        __syncthreads();
        if (i < NN) starts[i] = run + incl - v;
        if (threadIdx.x == 1023) s_running = run + incl;
        __syncthreads();
    }
    if (threadIdx.x == 0) starts[NN] = s_running;
}

__global__ void k_fill(const int* __restrict__ src, const int* __restrict__ dst,
                       const float* __restrict__ w, const int* __restrict__ starts,
                       int* __restrict__ cursor, int* __restrict__ csr_src, float* __restrict__ csr_w) {
    int e = blockIdx.x * 256 + threadIdx.x;
    if (e >= EE) return;
    int d = dst[e];
    int pos = atomicAdd(&cursor[d], 1);
    int slot = starts[d] + pos;
    csr_src[slot] = src[e];
    csr_w[slot] = w[e];
}

// ---------------- GNN hops (pull, wave-per-node) ----------------
__global__ __launch_bounds__(256) void k_hop1(
    const float* __restrict__ cp, const float* __restrict__ op,
    const int* __restrict__ starts, const int* __restrict__ csr_src, const float* __restrict__ csr_w,
    float* __restrict__ g1c, float* __restrict__ g1o)
{
    const int lane = threadIdx.x & 63;
    const int node = blockIdx.x * 4 + (threadIdx.x >> 6);
    const int f = lane * 2;
    const int s0 = starts[node];
    const int s1 = starts[node + 1];
    float2 acc_c = {0.f, 0.f}, acc_o = {0.f, 0.f};
    for (int i = s0; i < s1; ++i) {
        int s = csr_src[i];
        float w = csr_w[i];
        float2 vc = *(const float2*)&cp[(size_t)s * HH + f];
        float2 vo = *(const float2*)&op[(size_t)s * HH + f];
        acc_c.x = fmaf(w, vc.x, acc_c.x);
        acc_c.y = fmaf(w, vc.y, acc_c.y);
        acc_o.x = fmaf(w, vo.x, acc_o.x);
        acc_o.y = fmaf(w, vo.y, acc_o.y);
    }
    *(float2*)&g1c[(size_t)node * HH + f] = acc_c;
    *(float2*)&g1o[(size_t)node * HH + f] = acc_o;
}

__global__ __launch_bounds__(256) void k_hop2(
    const float* __restrict__ g1c, const float* __restrict__ g1o,
    const float* __restrict__ cp, const float* __restrict__ op,
    const float* __restrict__ bc, const float* __restrict__ bo,
    const int* __restrict__ starts, const int* __restrict__ csr_src, const float* __restrict__ csr_w,
    float* __restrict__ out)
{
    const int lane = threadIdx.x & 63;
    const int node = blockIdx.x * 4 + (threadIdx.x >> 6);
    const int f = lane * 2;
    const int s0 = starts[node];
    const int s1 = starts[node + 1];
    float2 acc_c = {0.f, 0.f}, acc_o = {0.f, 0.f};
    for (int i = s0; i < s1; ++i) {
        int s = csr_src[i];
        float w = csr_w[i];
        float2 vc = *(const float2*)&g1c[(size_t)s * HH + f];
        float2 vo = *(const float2*)&g1o[(size_t)s * HH + f];
        acc_c.x = fmaf(w, vc.x, acc_c.x);
        acc_c.y = fmaf(w, vc.y, acc_c.y);
        acc_o.x = fmaf(w, vo.x, acc_o.x);
        acc_o.y = fmaf(w, vo.y, acc_o.y);
    }
    float2 cpv = *(const float2*)&cp[(size_t)node * HH + f];
    float2 bcv = *(const float2*)&bc[f];
    float2 opv = *(const float2*)&op[(size_t)node * HH + f];
    float2 bov = *(const float2*)&bo[f];
    float2 rc = { acc_c.x + cpv.x + bcv.x, acc_c.y + cpv.y + bcv.y };
    float2 ro = { fmaxf(acc_o.x + opv.x + bov.x, 0.f), fmaxf(acc_o.y + opv.y + bov.y, 0.f) };
    *(float2*)&out[(size_t)node * HH + f] = rc;
    *(float2*)&out[(size_t)(NN + node) * HH + f] = ro;
}

// ---------------- launch ----------------
extern "C" void kernel_launch(void* const* d_in, const int* in_sizes, int n_in,
                              void* d_out, int out_size, void* d_ws, size_t ws_size,
                              hipStream_t stream)
{
    const float* x   = (const float*)d_in[0];
    const int*   ei  = (const int*)d_in[1];
    const float* ew  = (const float*)d_in[2];
    const float* Wac = (const float*)d_in[3];
    const float* bac = (const float*)d_in[4];
    const float* vac = (const float*)d_in[5];
    const float* Wao = (const float*)d_in[6];
    const float* bao = (const float*)d_in[7];
    const float* vao = (const float*)d_in[8];
    const float* Wc  = (const float*)d_in[9];
    const float* bc  = (const float*)d_in[10];
    const float* Wo  = (const float*)d_in[11];
    const float* bo  = (const float*)d_in[12];
    float* out = (float*)d_out;

    char* ws = (char*)d_ws;
    float* cp     = (float*)(ws + 0);
    float* op     = (float*)(ws + 25600000);
    float* g1c    = (float*)(ws + 51200000);
    float* g1o    = (float*)(ws + 76800000);
    int*   counts = (int*)(ws + 102400000);   // N ints
    int*   starts = (int*)(ws + 102600064);   // N+1 ints
    int*   cursor = (int*)(ws + 102800128);   // N ints
    int*   csr_src= (int*)(ws + 103000192);   // E ints
    float* csr_w  = (float*)(ws + 106200192); // E floats  (end ~109.4 MB)

    const int* src = ei;
    const int* dst = ei + EE;

    hipMemsetAsync(counts, 0, NN * sizeof(int), stream);
    hipMemsetAsync(cursor, 0, NN * sizeof(int), stream);

    k_count<<<(EE + 255) / 256, 256, 0, stream>>>(dst, counts);
    k_scan<<<1, 1024, 0, stream>>>(counts, starts);
    k_fill<<<(EE + 255) / 256, 256, 0, stream>>>(src, dst, ew, starts, cursor, csr_src, csr_w);
    k_att<<<NN / GG, 256, 0, stream>>>(x, Wac, bac, vac, Wao, bao, vao, Wc, Wo, cp, op);
    k_hop1<<<NN / 4, 256, 0, stream>>>(cp, op, starts, csr_src, csr_w, g1c, g1o);
    k_hop2<<<NN / 4, 256, 0, stream>>>(g1c, g1o, cp, op, bc, bo, starts, csr_src, csr_w, out);
}

// Round 3
// 851.254 us; speedup vs baseline: 1.8686x; 1.8686x over previous
//
#include <hip/hip_runtime.h>
#include <hip/hip_bf16.h>
#include <cstdint>

#define NN 50000
#define TT 8
#define DD 256
#define HH 128
#define EE 800000

typedef float f32x4 __attribute__((ext_vector_type(4)));
typedef short s16x8 __attribute__((ext_vector_type(8)));

__device__ inline unsigned short f2bf(float f) {
    union { float f; unsigned u; } c; c.f = f;
    unsigned r = c.u + 0x7FFF + ((c.u >> 16) & 1);
    return (unsigned short)(r >> 16);
}
__device__ inline float bf2f(short h) {
    union { unsigned u; float f; } c; c.u = ((unsigned)(unsigned short)h) << 16;
    return c.f;
}

// ---------------- weight pre-swizzle: fragment-ready bf16 B layout ----------------
// Bsw[kt][ct][lane][8j] = W[kt*32 + (lane>>4)*8 + j][(ct&7)*16 + (lane&15)]
// ct 0..7 -> head c matrix, ct 8..15 -> head o matrix.
__global__ __launch_bounds__(256) void k_prew(
    const float* __restrict__ Wac, const float* __restrict__ Wao,
    const float* __restrict__ Wc,  const float* __restrict__ Wo,
    short* __restrict__ Bsw1, short* __restrict__ Bsw2)
{
    int t = blockIdx.x * 256 + threadIdx.x;       // 0..16383
    int mat = t >> 13;
    int r = t & 8191;
    int kt = r >> 10;
    int ct = (r >> 6) & 15;
    int lane = r & 63;
    int g = lane >> 4, lr = lane & 15;
    const float* W = mat ? (ct < 8 ? Wc : Wo) : (ct < 8 ? Wac : Wao);
    int c = (ct & 7) * 16 + lr;
    short* out = (mat ? Bsw2 : Bsw1) + ((size_t)((kt * 16 + ct) * 64 + lane)) * 8;
    #pragma unroll
    for (int j = 0; j < 8; ++j) {
        int k = kt * 32 + g * 8 + j;
        out[j] = (short)f2bf(W[k * HH + c]);
    }
}

// ---------------- fused attention (MFMA) ----------------
// block: 16 nodes = 128 rows of x[N*T, 256]. wave w: rows w*32..w*32+31, all 256 cols.
__global__ __launch_bounds__(256) void k_att2(
    const float* __restrict__ x,
    const short* __restrict__ Bsw1, const short* __restrict__ Bsw2,
    const float* __restrict__ bac, const float* __restrict__ vac,
    const float* __restrict__ bao, const float* __restrict__ vao,
    float* __restrict__ cpo)
{
    __shared__ float e_lds[4][2][32];            // [wave][head][row_w]
    __shared__ short PL[2][8][4][16][8];         // [head][kt][g][node][j] bf16 = 16 KB
    const int tid = threadIdx.x;
    const int w = tid >> 6, lane = tid & 63;
    const int lr = lane & 15, g = lane >> 4;
    const size_t r0 = (size_t)blockIdx.x * 128 + w * 32;   // wave's global row base

    // ---- load A fragments straight from global (coalesced), fp32 -> bf16 ----
    s16x8 afr[2][8];
    #pragma unroll
    for (int rt = 0; rt < 2; ++rt) {
        const float* xr = x + (r0 + rt * 16 + lr) * DD;
        #pragma unroll
        for (int kt = 0; kt < 8; ++kt) {
            const float4* p = (const float4*)(xr + kt * 32 + g * 8);
            float4 u0 = p[0], u1 = p[1];
            s16x8 a;
            a[0] = (short)f2bf(u0.x); a[1] = (short)f2bf(u0.y);
            a[2] = (short)f2bf(u0.z); a[3] = (short)f2bf(u0.w);
            a[4] = (short)f2bf(u1.x); a[5] = (short)f2bf(u1.y);
            a[6] = (short)f2bf(u1.z); a[7] = (short)f2bf(u1.w);
            afr[rt][kt] = a;
        }
    }

    // ---- GEMM1: h = x @ [Wac|Wao], fused tanh + v-dot epilogue ----
    float ep[2][2][4];                           // [head][rt][i]
    #pragma unroll
    for (int h = 0; h < 2; ++h)
        #pragma unroll
        for (int rt = 0; rt < 2; ++rt)
            #pragma unroll
            for (int i = 0; i < 4; ++i) ep[h][rt][i] = 0.f;

    const s16x8* B1 = (const s16x8*)Bsw1;
    #pragma unroll
    for (int ct = 0; ct < 16; ++ct) {
        f32x4 acc0 = {0.f, 0.f, 0.f, 0.f}, acc1 = {0.f, 0.f, 0.f, 0.f};
        #pragma unroll
        for (int kt = 0; kt < 8; ++kt) {
            s16x8 bf = B1[(kt * 16 + ct) * 64 + lane];
            acc0 = __builtin_amdgcn_mfma_f32_16x16x32_bf16(afr[0][kt], bf, acc0, 0, 0, 0);
            acc1 = __builtin_amdgcn_mfma_f32_16x16x32_bf16(afr[1][kt], bf, acc1, 0, 0, 0);
        }
        const int head = ct >> 3;
        const int jj = (ct & 7) * 16 + lr;
        float bb = head ? bao[jj] : bac[jj];
        float vv = head ? vao[jj] : vac[jj];
        #pragma unroll
        for (int i = 0; i < 4; ++i) {
            float e0 = __expf(2.f * (acc0[i] + bb));
            float e1 = __expf(2.f * (acc1[i] + bb));
            float t0 = (e0 - 1.f) * __builtin_amdgcn_rcpf(e0 + 1.f);
            float t1 = (e1 - 1.f) * __builtin_amdgcn_rcpf(e1 + 1.f);
            ep[head][0][i] += t0 * vv;
            ep[head][1][i] += t1 * vv;
        }
    }

    // reduce e over the 16 col-lanes (lr), then publish per-wave rows
    #pragma unroll
    for (int h = 0; h < 2; ++h)
        #pragma unroll
        for (int rt = 0; rt < 2; ++rt)
            #pragma unroll
            for (int i = 0; i < 4; ++i) {
                float v = ep[h][rt][i];
                v += __shfl_xor(v, 1); v += __shfl_xor(v, 2);
                v += __shfl_xor(v, 4); v += __shfl_xor(v, 8);
                ep[h][rt][i] = v;
            }
    if (lr == 0) {
        #pragma unroll
        for (int h = 0; h < 2; ++h)
            #pragma unroll
            for (int rt = 0; rt < 2; ++rt)
                #pragma unroll
                for (int i = 0; i < 4; ++i)
                    e_lds[w][h][rt * 16 + g * 4 + i] = ep[h][rt][i];
    }
    __syncthreads();

    // ---- softmax coefficient for this lane's A-frag rows (row_w = rt*16+lr) ----
    float av[2][2];
    #pragma unroll
    for (int h = 0; h < 2; ++h) {
        #pragma unroll
        for (int rt = 0; rt < 2; ++rt) {
            int rw = rt * 16 + lr;
            int nb = rw & ~7;
            float m = -1e30f;
            #pragma unroll
            for (int u = 0; u < 8; ++u) m = fmaxf(m, e_lds[w][h][nb + u]);
            float s = 0.f;
            #pragma unroll
            for (int u = 0; u < 8; ++u) s += __expf(e_lds[w][h][nb + u] - m);
            float ee = e_lds[w][h][rw];
            av[h][rt] = __expf(ee - m) * __builtin_amdgcn_rcpf(s);
        }
    }

    // ---- pooling: pooled[node][k] = sum_t a[row] * x[row][k] (shfl over 8 t-lanes) ----
    #pragma unroll
    for (int kt = 0; kt < 8; ++kt) {
        #pragma unroll
        for (int rt = 0; rt < 2; ++rt) {
            float xf[8];
            #pragma unroll
            for (int j = 0; j < 8; ++j) xf[j] = bf2f(afr[rt][kt][j]);
            #pragma unroll
            for (int h = 0; h < 2; ++h) {
                float p[8];
                #pragma unroll
                for (int j = 0; j < 8; ++j) p[j] = av[h][rt] * xf[j];
                #pragma unroll
                for (int j = 0; j < 8; ++j) {
                    p[j] += __shfl_xor(p[j], 1);
                    p[j] += __shfl_xor(p[j], 2);
                    p[j] += __shfl_xor(p[j], 4);
                }
                if ((lane & 7) == 0) {
                    int node = w * 4 + rt * 2 + ((lane >> 3) & 1);
                    s16x8 pv;
                    #pragma unroll
                    for (int j = 0; j < 8; ++j) pv[j] = (short)f2bf(p[j]);
                    *(s16x8*)&PL[h][kt][g][node][0] = pv;
                }
            }
        }
    }
    __syncthreads();

    // ---- GEMM2: cpo[16 nodes][256] = pooled_{c|o} @ [Wc|Wo] ----
    const int head = w >> 1;                      // waves 0,1 -> c cols, 2,3 -> o cols
    s16x8 a2[8];
    #pragma unroll
    for (int kt = 0; kt < 8; ++kt)
        a2[kt] = *(const s16x8*)&PL[head][kt][g][lr][0];

    const s16x8* B2 = (const s16x8*)Bsw2;
    f32x4 acc2[4];
    #pragma unroll
    for (int c2 = 0; c2 < 4; ++c2) {
        acc2[c2] = (f32x4){0.f, 0.f, 0.f, 0.f};
        int ct = w * 4 + c2;
        #pragma unroll
        for (int kt = 0; kt < 8; ++kt) {
            s16x8 bf = B2[(kt * 16 + ct) * 64 + lane];
            acc2[c2] = __builtin_amdgcn_mfma_f32_16x16x32_bf16(a2[kt], bf, acc2[c2], 0, 0, 0);
        }
    }
    const int n0 = blockIdx.x * 16;
    #pragma unroll
    for (int c2 = 0; c2 < 4; ++c2) {
        int col = w * 64 + c2 * 16 + lr;
        #pragma unroll
        for (int i = 0; i < 4; ++i) {
            int node = n0 + g * 4 + i;
            cpo[(size_t)node * 256 + col] = acc2[c2][i];
        }
    }
}

// ---------------- CSR build ----------------
__global__ void k_count(const int* __restrict__ dst, int* __restrict__ counts) {
    int e = blockIdx.x * 256 + threadIdx.x;
    if (e < EE) atomicAdd(&counts[dst[e]], 1);
}

__global__ __launch_bounds__(1024) void k_scan(const int* __restrict__ counts, int* __restrict__ starts) {
    __shared__ int sdata[1024];
    __shared__ int s_running;
    if (threadIdx.x == 0) s_running = 0;
    __syncthreads();
    const int nChunks = (NN + 1023) / 1024;
    for (int c = 0; c < nChunks; ++c) {
        int i = c * 1024 + threadIdx.x;
        int v = (i < NN) ? counts[i] : 0;
        sdata[threadIdx.x] = v;
        __syncthreads();
        for (int off = 1; off < 1024; off <<= 1) {
            int tv = (threadIdx.x >= off) ? sdata[threadIdx.x - off] : 0;
            __syncthreads();
            sdata[threadIdx.x] += tv;
            __syncthreads();
        }
        int incl = sdata[threadIdx.x];
        int run = s_running;
        __syncthreads();
        if (i < NN) starts[i] = run + incl - v;
        if (threadIdx.x == 1023) s_running = run + incl;
        __syncthreads();
    }
    if (threadIdx.x == 0) starts[NN] = s_running;
}

__global__ void k_fill(const int* __restrict__ src, const int* __restrict__ dst,
                       const float* __restrict__ w, const int* __restrict__ starts,
                       int* __restrict__ cursor, int* __restrict__ csr_src, float* __restrict__ csr_w) {
    int e = blockIdx.x * 256 + threadIdx.x;
    if (e >= EE) return;
    int d = dst[e];
    int pos = atomicAdd(&cursor[d], 1);
    int slot = starts[d] + pos;
    csr_src[slot] = src[e];
    csr_w[slot] = w[e];
}

// ---------------- GNN hops (pull, wave-per-node, combined c|o rows) ----------------
__global__ __launch_bounds__(256) void k_hop1(
    const float* __restrict__ cpo,
    const int* __restrict__ starts, const int* __restrict__ csr_src, const float* __restrict__ csr_w,
    float* __restrict__ g1)
{
    const int lane = threadIdx.x & 63;
    const int node = blockIdx.x * 4 + (threadIdx.x >> 6);
    const int s0 = starts[node];
    const int s1 = starts[node + 1];
    const float4* src4 = (const float4*)cpo;
    float4 acc = {0.f, 0.f, 0.f, 0.f};
    for (int i = s0; i < s1; ++i) {
        int s = csr_src[i];
        float wt = csr_w[i];
        float4 v = src4[(size_t)s * 64 + lane];
        acc.x = fmaf(wt, v.x, acc.x);
        acc.y = fmaf(wt, v.y, acc.y);
        acc.z = fmaf(wt, v.z, acc.z);
        acc.w = fmaf(wt, v.w, acc.w);
    }
    ((float4*)g1)[(size_t)node * 64 + lane] = acc;
}

__global__ __launch_bounds__(256) void k_hop2(
    const float* __restrict__ g1, const float* __restrict__ cpo,
    const float* __restrict__ bc, const float* __restrict__ bo,
    const int* __restrict__ starts, const int* __restrict__ csr_src, const float* __restrict__ csr_w,
    float* __restrict__ out)
{
    const int lane = threadIdx.x & 63;
    const int node = blockIdx.x * 4 + (threadIdx.x >> 6);
    const int s0 = starts[node];
    const int s1 = starts[node + 1];
    const float4* src4 = (const float4*)g1;
    float4 acc = {0.f, 0.f, 0.f, 0.f};
    for (int i = s0; i < s1; ++i) {
        int s = csr_src[i];
        float wt = csr_w[i];
        float4 v = src4[(size_t)s * 64 + lane];
        acc.x = fmaf(wt, v.x, acc.x);
        acc.y = fmaf(wt, v.y, acc.y);
        acc.z = fmaf(wt, v.z, acc.z);
        acc.w = fmaf(wt, v.w, acc.w);
    }
    float4 r = ((const float4*)cpo)[(size_t)node * 64 + lane];
    float4 b = (lane < 32) ? ((const float4*)bc)[lane] : ((const float4*)bo)[lane - 32];
    r.x += acc.x + b.x; r.y += acc.y + b.y; r.z += acc.z + b.z; r.w += acc.w + b.w;
    float4* out4 = (float4*)out;
    if (lane < 32) {
        out4[(size_t)node * 32 + lane] = r;
    } else {
        r.x = fmaxf(r.x, 0.f); r.y = fmaxf(r.y, 0.f);
        r.z = fmaxf(r.z, 0.f); r.w = fmaxf(r.w, 0.f);
        out4[(size_t)NN * 32 + (size_t)node * 32 + (lane - 32)] = r;
    }
}

// ---------------- launch ----------------
extern "C" void kernel_launch(void* const* d_in, const int* in_sizes, int n_in,
                              void* d_out, int out_size, void* d_ws, size_t ws_size,
                              hipStream_t stream)
{
    const float* x   = (const float*)d_in[0];
    const int*   ei  = (const int*)d_in[1];
    const float* ew  = (const float*)d_in[2];
    const float* Wac = (const float*)d_in[3];
    const float* bac = (const float*)d_in[4];
    const float* vac = (const float*)d_in[5];
    const float* Wao = (const float*)d_in[6];
    const float* bao = (const float*)d_in[7];
    const float* vao = (const float*)d_in[8];
    const float* Wc  = (const float*)d_in[9];
    const float* bc  = (const float*)d_in[10];
    const float* Wo  = (const float*)d_in[11];
    const float* bo  = (const float*)d_in[12];
    float* out = (float*)d_out;

    char* ws = (char*)d_ws;
    float* cpo    = (float*)(ws + 0);            // [N][256] = 51.2 MB
    float* g1     = (float*)(ws + 51200000);     // [N][256] = 51.2 MB
    short* Bsw1   = (short*)(ws + 51200000);     // 128 KB, aliases g1 (dead until hop1)
    short* Bsw2   = (short*)(ws + 51331072);     // 128 KB
    int*   counts = (int*)(ws + 102400000);
    int*   starts = (int*)(ws + 102600064);
    int*   cursor = (int*)(ws + 102800128);
    int*   csr_src= (int*)(ws + 103000192);
    float* csr_w  = (float*)(ws + 106200192);    // end ~109.4 MB

    const int* src = ei;
    const int* dst = ei + EE;

    hipMemsetAsync(counts, 0, NN * sizeof(int), stream);
    hipMemsetAsync(cursor, 0, NN * sizeof(int), stream);

    k_prew<<<64, 256, 0, stream>>>(Wac, Wao, Wc, Wo, Bsw1, Bsw2);
    k_count<<<(EE + 255) / 256, 256, 0, stream>>>(dst, counts);
    k_scan<<<1, 1024, 0, stream>>>(counts, starts);
    k_fill<<<(EE + 255) / 256, 256, 0, stream>>>(src, dst, ew, starts, cursor, csr_src, csr_w);
    k_att2<<<NN / 16, 256, 0, stream>>>(x, Bsw1, Bsw2, bac, vac, bao, vao, cpo);
    k_hop1<<<NN / 4, 256, 0, stream>>>(cpo, starts, csr_src, csr_w, g1);
    k_hop2<<<NN / 4, 256, 0, stream>>>(g1, cpo, bc, bo, starts, csr_src, csr_w, out);
}

// Round 4
// 661.606 us; speedup vs baseline: 2.4042x; 1.2866x over previous
//
#include <hip/hip_runtime.h>
#include <hip/hip_bf16.h>
#include <cstdint>

#define NN 50000
#define TT 8
#define DD 256
#define HH 128
#define EE 800000

typedef float f32x4 __attribute__((ext_vector_type(4)));
typedef short s16x8 __attribute__((ext_vector_type(8)));

__device__ inline unsigned short f2bf(float f) {
    union { float f; unsigned u; } c; c.f = f;
    unsigned r = c.u + 0x7FFF + ((c.u >> 16) & 1);
    return (unsigned short)(r >> 16);
}
__device__ inline float bf2f(short h) {
    union { unsigned u; float f; } c; c.u = ((unsigned)(unsigned short)h) << 16;
    return c.f;
}

// ---------------- weight pre-swizzle: fragment-ready bf16 B layout ----------------
// Bsw[kt][ct][lane][8j] = W[kt*32 + (lane>>4)*8 + j][(ct&7)*16 + (lane&15)]
// ct 0..7 -> head c matrix, ct 8..15 -> head o matrix.
__global__ __launch_bounds__(256) void k_prew(
    const float* __restrict__ Wac, const float* __restrict__ Wao,
    const float* __restrict__ Wc,  const float* __restrict__ Wo,
    short* __restrict__ Bsw1, short* __restrict__ Bsw2)
{
    int t = blockIdx.x * 256 + threadIdx.x;       // 0..16383
    int mat = t >> 13;
    int r = t & 8191;
    int kt = r >> 10;
    int ct = (r >> 6) & 15;
    int lane = r & 63;
    int g = lane >> 4, lr = lane & 15;
    const float* W = mat ? (ct < 8 ? Wc : Wo) : (ct < 8 ? Wac : Wao);
    int c = (ct & 7) * 16 + lr;
    short* out = (mat ? Bsw2 : Bsw1) + ((size_t)((kt * 16 + ct) * 64 + lane)) * 8;
    #pragma unroll
    for (int j = 0; j < 8; ++j) {
        int k = kt * 32 + g * 8 + j;
        out[j] = (short)f2bf(W[k * HH + c]);
    }
}

// ---------------- fused attention (MFMA, LDS-staged) ----------------
// block: 8 nodes = 64 rows of x[N*T, 256]. 4 waves; wave w owns rows w*16..w*16+15.
__global__ __launch_bounds__(256, 3) void k_att3(
    const float* __restrict__ x,
    const short* __restrict__ Bsw1, const short* __restrict__ Bsw2,
    const float* __restrict__ bac, const float* __restrict__ vac,
    const float* __restrict__ bao, const float* __restrict__ vao,
    float* __restrict__ cpo)
{
    __shared__ short xs[64 * 256];      // bf16, XOR-16B swizzled, 32 KB
    __shared__ float e_lds[2][64];      // raw attention logits per row
    __shared__ float av_lds[2][64];     // softmax coefficient per row
    __shared__ short PL[2 * 8 * 4 * 8 * 8];  // pooled bf16 in A-frag layout, 8 KB
    const int tid = threadIdx.x;
    const int w = tid >> 6, lane = tid & 63;
    const int lr = lane & 15, g = lane >> 4;

    // ---- stage 64 rows of x to LDS as bf16 (coalesced, all loads in flight) ----
    {
        const float* xb = x + (size_t)blockIdx.x * (64 * 256);
        float4 va[8], vb[8];
        #pragma unroll
        for (int k = 0; k < 8; ++k) {
            int u = k * 256 + tid;                  // 8-float unit index
            const float4* p = (const float4*)(xb + (size_t)u * 8);
            va[k] = p[0]; vb[k] = p[1];
        }
        #pragma unroll
        for (int k = 0; k < 8; ++k) {
            int u = k * 256 + tid;
            int row = u >> 5, cu = u & 31;
            s16x8 s;
            s[0] = (short)f2bf(va[k].x); s[1] = (short)f2bf(va[k].y);
            s[2] = (short)f2bf(va[k].z); s[3] = (short)f2bf(va[k].w);
            s[4] = (short)f2bf(vb[k].x); s[5] = (short)f2bf(vb[k].y);
            s[6] = (short)f2bf(vb[k].z); s[7] = (short)f2bf(vb[k].w);
            int byte = row * 512 + ((cu * 16) ^ ((row & 7) << 4));
            *(s16x8*)((char*)xs + byte) = s;
        }
    }
    __syncthreads();

    // ---- A fragments from LDS ----
    s16x8 afr[8];
    {
        char* base = (char*)xs + (w * 16 + lr) * 512;
        const int sw = (lr & 7) << 4;
        #pragma unroll
        for (int kt = 0; kt < 8; ++kt)
            afr[kt] = *(const s16x8*)(base + ((kt * 64 + g * 16) ^ sw));
    }

    // ---- GEMM1: h = x @ [Wac|Wao], fused tanh + v-dot epilogue ----
    float ep[2][4];
    #pragma unroll
    for (int h = 0; h < 2; ++h)
        #pragma unroll
        for (int i = 0; i < 4; ++i) ep[h][i] = 0.f;

    const s16x8* B1 = (const s16x8*)Bsw1;
    #pragma unroll
    for (int ct = 0; ct < 16; ++ct) {
        f32x4 acc = {0.f, 0.f, 0.f, 0.f};
        #pragma unroll
        for (int kt = 0; kt < 8; ++kt)
            acc = __builtin_amdgcn_mfma_f32_16x16x32_bf16(afr[kt], B1[(kt * 16 + ct) * 64 + lane], acc, 0, 0, 0);
        const int head = ct >> 3;
        const int jj = (ct & 7) * 16 + lr;
        float bb = head ? bao[jj] : bac[jj];
        float vv = head ? vao[jj] : vac[jj];
        #pragma unroll
        for (int i = 0; i < 4; ++i) {
            float e = __expf(2.f * (acc[i] + bb));
            float t = (e - 1.f) * __builtin_amdgcn_rcpf(e + 1.f);
            ep[head][i] += t * vv;
        }
    }

    // reduce e over the 16 col-lanes (lr), publish per-row logits
    #pragma unroll
    for (int h = 0; h < 2; ++h)
        #pragma unroll
        for (int i = 0; i < 4; ++i) {
            float v = ep[h][i];
            v += __shfl_xor(v, 1); v += __shfl_xor(v, 2);
            v += __shfl_xor(v, 4); v += __shfl_xor(v, 8);
            ep[h][i] = v;
        }
    if (lr == 0) {
        #pragma unroll
        for (int h = 0; h < 2; ++h)
            #pragma unroll
            for (int i = 0; i < 4; ++i)
                e_lds[h][w * 16 + g * 4 + i] = ep[h][i];
    }
    __syncthreads();

    // ---- softmax coefficients (threads 0..127: one per (head,row)) ----
    if (tid < 128) {
        int h = tid >> 6, row = tid & 63, nb = row & ~7;
        float m = -1e30f;
        #pragma unroll
        for (int u = 0; u < 8; ++u) m = fmaxf(m, e_lds[h][nb + u]);
        float s = 0.f;
        #pragma unroll
        for (int u = 0; u < 8; ++u) s += __expf(e_lds[h][nb + u] - m);
        av_lds[h][row] = __expf(e_lds[h][row] - m) * __builtin_amdgcn_rcpf(s);
    }
    __syncthreads();

    // ---- pooling from LDS: thread = (node group, col pair) ----
    {
        const int d2 = tid & 127;          // col pair (cols 2*d2, 2*d2+1)
        const int nb = (tid >> 7) * 4;     // node base (0 or 4)
        float accp[2][4][2];
        #pragma unroll
        for (int h = 0; h < 2; ++h)
            #pragma unroll
            for (int nn = 0; nn < 4; ++nn) { accp[h][nn][0] = 0.f; accp[h][nn][1] = 0.f; }
        #pragma unroll
        for (int nn = 0; nn < 4; ++nn) {
            const int n = nb + nn;
            #pragma unroll
            for (int t = 0; t < 8; ++t) {
                int row = n * 8 + t;
                unsigned u = *(const unsigned*)((char*)xs + row * 512 + ((d2 * 4) ^ (t << 4)));
                float lo = bf2f((short)(u & 0xffff));
                float hi = bf2f((short)(u >> 16));
                float a0 = av_lds[0][row], a1 = av_lds[1][row];
                accp[0][nn][0] = fmaf(a0, lo, accp[0][nn][0]);
                accp[0][nn][1] = fmaf(a0, hi, accp[0][nn][1]);
                accp[1][nn][0] = fmaf(a1, lo, accp[1][nn][0]);
                accp[1][nn][1] = fmaf(a1, hi, accp[1][nn][1]);
            }
        }
        // write pooled bf16 pairs into PL in A-fragment layout
        int col = d2 * 2;
        int kt = col >> 5, gg = (col >> 3) & 3, jp = col & 7;
        #pragma unroll
        for (int h = 0; h < 2; ++h)
            #pragma unroll
            for (int nn = 0; nn < 4; ++nn) {
                int n = nb + nn;
                unsigned pv = (unsigned)f2bf(accp[h][nn][0]) | ((unsigned)f2bf(accp[h][nn][1]) << 16);
                int sidx = (((h * 8 + kt) * 4 + gg) * 8 + n) * 8 + jp;
                *(unsigned*)((char*)PL + sidx * 2) = pv;
            }
    }
    __syncthreads();

    // ---- GEMM2: cpo[8 nodes][256] = pooled_{c|o} @ [Wc|Wo] ----
    {
        const int head = w >> 1;           // waves 0,1 -> c cols, 2,3 -> o cols
        s16x8 a2[8];
        #pragma unroll
        for (int kt = 0; kt < 8; ++kt) {
            int sidx = (((head * 8 + kt) * 4 + g) * 8 + (lr & 7)) * 8;
            a2[kt] = *(const s16x8*)((char*)PL + sidx * 2);
        }
        const s16x8* B2 = (const s16x8*)Bsw2;
        const int n0 = blockIdx.x * 8;
        #pragma unroll
        for (int c2 = 0; c2 < 4; ++c2) {
            int ct = w * 4 + c2;
            f32x4 acc = {0.f, 0.f, 0.f, 0.f};
            #pragma unroll
            for (int kt = 0; kt < 8; ++kt)
                acc = __builtin_amdgcn_mfma_f32_16x16x32_bf16(a2[kt], B2[(kt * 16 + ct) * 64 + lane], acc, 0, 0, 0);
            if (g < 2) {
                int col = head * 128 + (ct & 7) * 16 + lr;
                #pragma unroll
                for (int i = 0; i < 4; ++i) {
                    int node = g * 4 + i;
                    cpo[(size_t)(n0 + node) * 256 + col] = acc[i];
                }
            }
        }
    }
}

// ---------------- CSR build ----------------
__global__ void k_count(const int* __restrict__ dst, int* __restrict__ counts) {
    int e = blockIdx.x * 256 + threadIdx.x;
    if (e < EE) atomicAdd(&counts[dst[e]], 1);
}

__global__ __launch_bounds__(1024) void k_scan(const int* __restrict__ counts, int* __restrict__ starts) {
    __shared__ int sdata[1024];
    __shared__ int s_running;
    if (threadIdx.x == 0) s_running = 0;
    __syncthreads();
    const int nChunks = (NN + 1023) / 1024;
    for (int c = 0; c < nChunks; ++c) {
        int i = c * 1024 + threadIdx.x;
        int v = (i < NN) ? counts[i] : 0;
        sdata[threadIdx.x] = v;
        __syncthreads();
        for (int off = 1; off < 1024; off <<= 1) {
            int tv = (threadIdx.x >= off) ? sdata[threadIdx.x - off] : 0;
            __syncthreads();
            sdata[threadIdx.x] += tv;
            __syncthreads();
        }
        int incl = sdata[threadIdx.x];
        int run = s_running;
        __syncthreads();
        if (i < NN) starts[i] = run + incl - v;
        if (threadIdx.x == 1023) s_running = run + incl;
        __syncthreads();
    }
    if (threadIdx.x == 0) starts[NN] = s_running;
}

__global__ void k_fill(const int* __restrict__ src, const int* __restrict__ dst,
                       const float* __restrict__ w, const int* __restrict__ starts,
                       int* __restrict__ cursor, int* __restrict__ csr_src, float* __restrict__ csr_w) {
    int e = blockIdx.x * 256 + threadIdx.x;
    if (e >= EE) return;
    int d = dst[e];
    int pos = atomicAdd(&cursor[d], 1);
    int slot = starts[d] + pos;
    csr_src[slot] = src[e];
    csr_w[slot] = w[e];
}

// ---------------- GNN hops (pull, wave-per-node, combined c|o rows) ----------------
__global__ __launch_bounds__(256) void k_hop1(
    const float* __restrict__ cpo,
    const int* __restrict__ starts, const int* __restrict__ csr_src, const float* __restrict__ csr_w,
    float* __restrict__ g1)
{
    const int lane = threadIdx.x & 63;
    const int node = blockIdx.x * 4 + (threadIdx.x >> 6);
    const int s0 = starts[node];
    const int s1 = starts[node + 1];
    const float4* src4 = (const float4*)cpo;
    float4 acc = {0.f, 0.f, 0.f, 0.f};
    int i = s0;
    for (; i + 1 < s1; i += 2) {
        int sA = csr_src[i], sB = csr_src[i + 1];
        float wA = csr_w[i], wB = csr_w[i + 1];
        float4 vA = src4[(size_t)sA * 64 + lane];
        float4 vB = src4[(size_t)sB * 64 + lane];
        acc.x = fmaf(wA, vA.x, fmaf(wB, vB.x, acc.x));
        acc.y = fmaf(wA, vA.y, fmaf(wB, vB.y, acc.y));
        acc.z = fmaf(wA, vA.z, fmaf(wB, vB.z, acc.z));
        acc.w = fmaf(wA, vA.w, fmaf(wB, vB.w, acc.w));
    }
    if (i < s1) {
        int sA = csr_src[i];
        float wA = csr_w[i];
        float4 vA = src4[(size_t)sA * 64 + lane];
        acc.x = fmaf(wA, vA.x, acc.x);
        acc.y = fmaf(wA, vA.y, acc.y);
        acc.z = fmaf(wA, vA.z, acc.z);
        acc.w = fmaf(wA, vA.w, acc.w);
    }
    ((float4*)g1)[(size_t)node * 64 + lane] = acc;
}

__global__ __launch_bounds__(256) void k_hop2(
    const float* __restrict__ g1, const float* __restrict__ cpo,
    const float* __restrict__ bc, const float* __restrict__ bo,
    const int* __restrict__ starts, const int* __restrict__ csr_src, const float* __restrict__ csr_w,
    float* __restrict__ out)
{
    const int lane = threadIdx.x & 63;
    const int node = blockIdx.x * 4 + (threadIdx.x >> 6);
    const int s0 = starts[node];
    const int s1 = starts[node + 1];
    const float4* src4 = (const float4*)g1;
    float4 acc = {0.f, 0.f, 0.f, 0.f};
    int i = s0;
    for (; i + 1 < s1; i += 2) {
        int sA = csr_src[i], sB = csr_src[i + 1];
        float wA = csr_w[i], wB = csr_w[i + 1];
        float4 vA = src4[(size_t)sA * 64 + lane];
        float4 vB = src4[(size_t)sB * 64 + lane];
        acc.x = fmaf(wA, vA.x, fmaf(wB, vB.x, acc.x));
        acc.y = fmaf(wA, vA.y, fmaf(wB, vB.y, acc.y));
        acc.z = fmaf(wA, vA.z, fmaf(wB, vB.z, acc.z));
        acc.w = fmaf(wA, vA.w, fmaf(wB, vB.w, acc.w));
    }
    if (i < s1) {
        int sA = csr_src[i];
        float wA = csr_w[i];
        float4 vA = src4[(size_t)sA * 64 + lane];
        acc.x = fmaf(wA, vA.x, acc.x);
        acc.y = fmaf(wA, vA.y, acc.y);
        acc.z = fmaf(wA, vA.z, acc.z);
        acc.w = fmaf(wA, vA.w, acc.w);
    }
    float4 r = ((const float4*)cpo)[(size_t)node * 64 + lane];
    float4 b = (lane < 32) ? ((const float4*)bc)[lane] : ((const float4*)bo)[lane - 32];
    r.x += acc.x + b.x; r.y += acc.y + b.y; r.z += acc.z + b.z; r.w += acc.w + b.w;
    float4* out4 = (float4*)out;
    if (lane < 32) {
        out4[(size_t)node * 32 + lane] = r;
    } else {
        r.x = fmaxf(r.x, 0.f); r.y = fmaxf(r.y, 0.f);
        r.z = fmaxf(r.z, 0.f); r.w = fmaxf(r.w, 0.f);
        out4[(size_t)NN * 32 + (size_t)node * 32 + (lane - 32)] = r;
    }
}

// ---------------- launch ----------------
extern "C" void kernel_launch(void* const* d_in, const int* in_sizes, int n_in,
                              void* d_out, int out_size, void* d_ws, size_t ws_size,
                              hipStream_t stream)
{
    const float* x   = (const float*)d_in[0];
    const int*   ei  = (const int*)d_in[1];
    const float* ew  = (const float*)d_in[2];
    const float* Wac = (const float*)d_in[3];
    const float* bac = (const float*)d_in[4];
    const float* vac = (const float*)d_in[5];
    const float* Wao = (const float*)d_in[6];
    const float* bao = (const float*)d_in[7];
    const float* vao = (const float*)d_in[8];
    const float* Wc  = (const float*)d_in[9];
    const float* bc  = (const float*)d_in[10];
    const float* Wo  = (const float*)d_in[11];
    const float* bo  = (const float*)d_in[12];
    float* out = (float*)d_out;

    char* ws = (char*)d_ws;
    float* cpo    = (float*)(ws + 0);            // [N][256] = 51.2 MB
    float* g1     = (float*)(ws + 51200000);     // [N][256] = 51.2 MB
    short* Bsw1   = (short*)(ws + 51200000);     // 128 KB, aliases g1 (dead until hop1)
    short* Bsw2   = (short*)(ws + 51331072);     // 128 KB
    int*   counts = (int*)(ws + 102400000);
    int*   starts = (int*)(ws + 102600064);
    int*   cursor = (int*)(ws + 102800128);
    int*   csr_src= (int*)(ws + 103000192);
    float* csr_w  = (float*)(ws + 106200192);    // end ~109.4 MB

    const int* src = ei;
    const int* dst = ei + EE;

    hipMemsetAsync(counts, 0, NN * sizeof(int), stream);
    hipMemsetAsync(cursor, 0, NN * sizeof(int), stream);

    k_prew<<<64, 256, 0, stream>>>(Wac, Wao, Wc, Wo, Bsw1, Bsw2);
    k_count<<<(EE + 255) / 256, 256, 0, stream>>>(dst, counts);
    k_scan<<<1, 1024, 0, stream>>>(counts, starts);
    k_fill<<<(EE + 255) / 256, 256, 0, stream>>>(src, dst, ew, starts, cursor, csr_src, csr_w);
    k_att3<<<NN / 8, 256, 0, stream>>>(x, Bsw1, Bsw2, bac, vac, bao, vao, cpo);
    k_hop1<<<NN / 4, 256, 0, stream>>>(cpo, starts, csr_src, csr_w, g1);
    k_hop2<<<NN / 4, 256, 0, stream>>>(g1, cpo, bc, bo, starts, csr_src, csr_w, out);
}

// Round 5
// 522.838 us; speedup vs baseline: 3.0423x; 1.2654x over previous
//
#include <hip/hip_runtime.h>
#include <hip/hip_bf16.h>
#include <cstdint>

#define NN 50000
#define TT 8
#define DD 256
#define HH 128
#define EE 800000

typedef float f32x4 __attribute__((ext_vector_type(4)));
typedef short s16x8 __attribute__((ext_vector_type(8)));

__device__ inline unsigned short f2bf(float f) {
    union { float f; unsigned u; } c; c.f = f;
    unsigned r = c.u + 0x7FFF + ((c.u >> 16) & 1);
    return (unsigned short)(r >> 16);
}
__device__ inline float bf2f(unsigned short h) {
    union { unsigned u; float f; } c; c.u = ((unsigned)h) << 16;
    return c.f;
}
__device__ inline float4 u4tof4(ushort4 v) {
    return make_float4(bf2f(v.x), bf2f(v.y), bf2f(v.z), bf2f(v.w));
}

// ---------------- weight pre-swizzle: fragment-ready bf16 B layout ----------------
__global__ __launch_bounds__(256) void k_prew(
    const float* __restrict__ Wac, const float* __restrict__ Wao,
    const float* __restrict__ Wc,  const float* __restrict__ Wo,
    short* __restrict__ Bsw1, short* __restrict__ Bsw2)
{
    int t = blockIdx.x * 256 + threadIdx.x;       // 0..16383
    int mat = t >> 13;
    int r = t & 8191;
    int kt = r >> 10;
    int ct = (r >> 6) & 15;
    int lane = r & 63;
    int g = lane >> 4, lr = lane & 15;
    const float* W = mat ? (ct < 8 ? Wc : Wo) : (ct < 8 ? Wac : Wao);
    int c = (ct & 7) * 16 + lr;
    short* out = (mat ? Bsw2 : Bsw1) + ((size_t)((kt * 16 + ct) * 64 + lane)) * 8;
    #pragma unroll
    for (int j = 0; j < 8; ++j) {
        int k = kt * 32 + g * 8 + j;
        out[j] = (short)f2bf(W[k * HH + c]);
    }
}

// ---------------- fused attention (MFMA, LDS-staged, coalesced bf16 out) ----------------
// block: 8 nodes = 64 rows of x[N*T, 256]. 4 waves; wave w owns rows w*16..w*16+15.
__global__ __launch_bounds__(256, 3) void k_att3(
    const float* __restrict__ x,
    const short* __restrict__ Bsw1, const short* __restrict__ Bsw2,
    const float* __restrict__ bac, const float* __restrict__ vac,
    const float* __restrict__ bao, const float* __restrict__ vao,
    unsigned short* __restrict__ cpo_bf)
{
    __shared__ short xs[64 * 256];      // bf16, XOR-16B swizzled, 32 KB
    __shared__ float e_lds[2][64];      // raw attention logits per row
    __shared__ float av_lds[2][64];     // softmax coefficient per row
    __shared__ short PL[2 * 8 * 4 * 8 * 8];  // pooled bf16 in A-frag layout, 8 KB
    __shared__ unsigned short cob[8 * 256];  // GEMM2 output staging, bf16, 4 KB
    const int tid = threadIdx.x;
    const int w = tid >> 6, lane = tid & 63;
    const int lr = lane & 15, g = lane >> 4;

    // ---- stage 64 rows of x to LDS as bf16 (coalesced, all loads in flight) ----
    {
        const float* xb = x + (size_t)blockIdx.x * (64 * 256);
        float4 va[8], vb[8];
        #pragma unroll
        for (int k = 0; k < 8; ++k) {
            int u = k * 256 + tid;                  // 8-float unit index
            const float4* p = (const float4*)(xb + (size_t)u * 8);
            va[k] = p[0]; vb[k] = p[1];
        }
        #pragma unroll
        for (int k = 0; k < 8; ++k) {
            int u = k * 256 + tid;
            int row = u >> 5, cu = u & 31;
            s16x8 s;
            s[0] = (short)f2bf(va[k].x); s[1] = (short)f2bf(va[k].y);
            s[2] = (short)f2bf(va[k].z); s[3] = (short)f2bf(va[k].w);
            s[4] = (short)f2bf(vb[k].x); s[5] = (short)f2bf(vb[k].y);
            s[6] = (short)f2bf(vb[k].z); s[7] = (short)f2bf(vb[k].w);
            int byte = row * 512 + ((cu * 16) ^ ((row & 7) << 4));
            *(s16x8*)((char*)xs + byte) = s;
        }
    }
    __syncthreads();

    // ---- A fragments from LDS ----
    s16x8 afr[8];
    {
        char* base = (char*)xs + (w * 16 + lr) * 512;
        const int sw = (lr & 7) << 4;
        #pragma unroll
        for (int kt = 0; kt < 8; ++kt)
            afr[kt] = *(const s16x8*)(base + ((kt * 64 + g * 16) ^ sw));
    }

    // ---- GEMM1: h = x @ [Wac|Wao], fused tanh + v-dot epilogue ----
    float ep[2][4];
    #pragma unroll
    for (int h = 0; h < 2; ++h)
        #pragma unroll
        for (int i = 0; i < 4; ++i) ep[h][i] = 0.f;

    const s16x8* B1 = (const s16x8*)Bsw1;
    #pragma unroll
    for (int ct = 0; ct < 16; ++ct) {
        f32x4 acc = {0.f, 0.f, 0.f, 0.f};
        #pragma unroll
        for (int kt = 0; kt < 8; ++kt)
            acc = __builtin_amdgcn_mfma_f32_16x16x32_bf16(afr[kt], B1[(kt * 16 + ct) * 64 + lane], acc, 0, 0, 0);
        const int head = ct >> 3;
        const int jj = (ct & 7) * 16 + lr;
        float bb = head ? bao[jj] : bac[jj];
        float vv = head ? vao[jj] : vac[jj];
        #pragma unroll
        for (int i = 0; i < 4; ++i) {
            float e = __expf(2.f * (acc[i] + bb));
            float t = (e - 1.f) * __builtin_amdgcn_rcpf(e + 1.f);
            ep[head][i] += t * vv;
        }
    }

    // reduce e over the 16 col-lanes (lr), publish per-row logits
    #pragma unroll
    for (int h = 0; h < 2; ++h)
        #pragma unroll
        for (int i = 0; i < 4; ++i) {
            float v = ep[h][i];
            v += __shfl_xor(v, 1); v += __shfl_xor(v, 2);
            v += __shfl_xor(v, 4); v += __shfl_xor(v, 8);
            ep[h][i] = v;
        }
    if (lr == 0) {
        #pragma unroll
        for (int h = 0; h < 2; ++h)
            #pragma unroll
            for (int i = 0; i < 4; ++i)
                e_lds[h][w * 16 + g * 4 + i] = ep[h][i];
    }
    __syncthreads();

    // ---- softmax coefficients (threads 0..127: one per (head,row)) ----
    if (tid < 128) {
        int h = tid >> 6, row = tid & 63, nb = row & ~7;
        float m = -1e30f;
        #pragma unroll
        for (int u = 0; u < 8; ++u) m = fmaxf(m, e_lds[h][nb + u]);
        float s = 0.f;
        #pragma unroll
        for (int u = 0; u < 8; ++u) s += __expf(e_lds[h][nb + u] - m);
        av_lds[h][row] = __expf(e_lds[h][row] - m) * __builtin_amdgcn_rcpf(s);
    }
    __syncthreads();

    // ---- pooling from LDS: thread = (node group, col pair) ----
    {
        const int d2 = tid & 127;          // col pair (cols 2*d2, 2*d2+1)
        const int nb = (tid >> 7) * 4;     // node base (0 or 4)
        float accp[2][4][2];
        #pragma unroll
        for (int h = 0; h < 2; ++h)
            #pragma unroll
            for (int nn = 0; nn < 4; ++nn) { accp[h][nn][0] = 0.f; accp[h][nn][1] = 0.f; }
        #pragma unroll
        for (int nn = 0; nn < 4; ++nn) {
            const int n = nb + nn;
            #pragma unroll
            for (int t = 0; t < 8; ++t) {
                int row = n * 8 + t;
                unsigned u = *(const unsigned*)((char*)xs + row * 512 + ((d2 * 4) ^ (t << 4)));
                float lo = bf2f((unsigned short)(u & 0xffff));
                float hi = bf2f((unsigned short)(u >> 16));
                float a0 = av_lds[0][row], a1 = av_lds[1][row];
                accp[0][nn][0] = fmaf(a0, lo, accp[0][nn][0]);
                accp[0][nn][1] = fmaf(a0, hi, accp[0][nn][1]);
                accp[1][nn][0] = fmaf(a1, lo, accp[1][nn][0]);
                accp[1][nn][1] = fmaf(a1, hi, accp[1][nn][1]);
            }
        }
        // write pooled bf16 pairs into PL in A-fragment layout
        int col = d2 * 2;
        int kt = col >> 5, gg = (col >> 3) & 3, jp = col & 7;
        #pragma unroll
        for (int h = 0; h < 2; ++h)
            #pragma unroll
            for (int nn = 0; nn < 4; ++nn) {
                int n = nb + nn;
                unsigned pv = (unsigned)f2bf(accp[h][nn][0]) | ((unsigned)f2bf(accp[h][nn][1]) << 16);
                int sidx = (((h * 8 + kt) * 4 + gg) * 8 + n) * 8 + jp;
                *(unsigned*)((char*)PL + sidx * 2) = pv;
            }
    }
    __syncthreads();

    // ---- GEMM2: cob[8 nodes][256] = pooled_{c|o} @ [Wc|Wo] -> coalesced bf16 write ----
    {
        const int head = w >> 1;           // waves 0,1 -> c cols, 2,3 -> o cols
        s16x8 a2[8];
        #pragma unroll
        for (int kt = 0; kt < 8; ++kt) {
            int sidx = (((head * 8 + kt) * 4 + g) * 8 + (lr & 7)) * 8;
            a2[kt] = *(const s16x8*)((char*)PL + sidx * 2);
        }
        const s16x8* B2 = (const s16x8*)Bsw2;
        #pragma unroll
        for (int c2 = 0; c2 < 4; ++c2) {
            int ct = w * 4 + c2;
            f32x4 acc = {0.f, 0.f, 0.f, 0.f};
            #pragma unroll
            for (int kt = 0; kt < 8; ++kt)
                acc = __builtin_amdgcn_mfma_f32_16x16x32_bf16(a2[kt], B2[(kt * 16 + ct) * 64 + lane], acc, 0, 0, 0);
            if (g < 2) {
                int col = head * 128 + (ct & 7) * 16 + lr;
                #pragma unroll
                for (int i = 0; i < 4; ++i) {
                    int node = g * 4 + i;
                    cob[node * 256 + col] = f2bf(acc[i]);
                }
            }
        }
    }
    __syncthreads();

    // ---- coalesced block write: 8 nodes x 512 B ----
    {
        const size_t base = (size_t)blockIdx.x * 8 * 256;
        ((ushort4*)(cpo_bf + base))[tid * 2]     = ((const ushort4*)cob)[tid * 2];
        ((ushort4*)(cpo_bf + base))[tid * 2 + 1] = ((const ushort4*)cob)[tid * 2 + 1];
    }
}

// ---------------- CSR build ----------------
__global__ void k_count(const int* __restrict__ dst, int* __restrict__ counts) {
    int e = blockIdx.x * 256 + threadIdx.x;
    if (e < EE) atomicAdd(&counts[dst[e]], 1);
}

__global__ __launch_bounds__(1024) void k_scan(const int* __restrict__ counts, int* __restrict__ starts) {
    __shared__ int sdata[1024];
    __shared__ int s_running;
    if (threadIdx.x == 0) s_running = 0;
    __syncthreads();
    const int nChunks = (NN + 1023) / 1024;
    for (int c = 0; c < nChunks; ++c) {
        int i = c * 1024 + threadIdx.x;
        int v = (i < NN) ? counts[i] : 0;
        sdata[threadIdx.x] = v;
        __syncthreads();
        for (int off = 1; off < 1024; off <<= 1) {
            int tv = (threadIdx.x >= off) ? sdata[threadIdx.x - off] : 0;
            __syncthreads();
            sdata[threadIdx.x] += tv;
            __syncthreads();
        }
        int incl = sdata[threadIdx.x];
        int run = s_running;
        __syncthreads();
        if (i < NN) starts[i] = run + incl - v;
        if (threadIdx.x == 1023) s_running = run + incl;
        __syncthreads();
    }
    if (threadIdx.x == 0) starts[NN] = s_running;
}

__global__ void k_fill(const int* __restrict__ src, const int* __restrict__ dst,
                       const float* __restrict__ w, const int* __restrict__ starts,
                       int* __restrict__ cursor, int* __restrict__ csr_src, float* __restrict__ csr_w) {
    int e = blockIdx.x * 256 + threadIdx.x;
    if (e >= EE) return;
    int d = dst[e];
    int pos = atomicAdd(&cursor[d], 1);
    int slot = starts[d] + pos;
    csr_src[slot] = src[e];
    csr_w[slot] = w[e];
}

// ---------------- GNN hops (pull, wave-per-node, bf16 rows) ----------------
__global__ __launch_bounds__(256) void k_hop1(
    const unsigned short* __restrict__ cpo_bf,
    const int* __restrict__ starts, const int* __restrict__ csr_src, const float* __restrict__ csr_w,
    unsigned short* __restrict__ g1_bf)
{
    const int lane = threadIdx.x & 63;
    const int node = blockIdx.x * 4 + (threadIdx.x >> 6);
    const int f = lane * 4;
    const int s0 = starts[node];
    const int s1 = starts[node + 1];
    float4 acc = {0.f, 0.f, 0.f, 0.f};
    int i = s0;
    for (; i + 1 < s1; i += 2) {
        int sA = csr_src[i], sB = csr_src[i + 1];
        float wA = csr_w[i], wB = csr_w[i + 1];
        float4 vA = u4tof4(*(const ushort4*)&cpo_bf[(size_t)sA * 256 + f]);
        float4 vB = u4tof4(*(const ushort4*)&cpo_bf[(size_t)sB * 256 + f]);
        acc.x = fmaf(wA, vA.x, fmaf(wB, vB.x, acc.x));
        acc.y = fmaf(wA, vA.y, fmaf(wB, vB.y, acc.y));
        acc.z = fmaf(wA, vA.z, fmaf(wB, vB.z, acc.z));
        acc.w = fmaf(wA, vA.w, fmaf(wB, vB.w, acc.w));
    }
    if (i < s1) {
        int sA = csr_src[i];
        float wA = csr_w[i];
        float4 vA = u4tof4(*(const ushort4*)&cpo_bf[(size_t)sA * 256 + f]);
        acc.x = fmaf(wA, vA.x, acc.x);
        acc.y = fmaf(wA, vA.y, acc.y);
        acc.z = fmaf(wA, vA.z, acc.z);
        acc.w = fmaf(wA, vA.w, acc.w);
    }
    ushort4 o;
    o.x = f2bf(acc.x); o.y = f2bf(acc.y); o.z = f2bf(acc.z); o.w = f2bf(acc.w);
    *(ushort4*)&g1_bf[(size_t)node * 256 + f] = o;
}

__global__ __launch_bounds__(256) void k_hop2(
    const unsigned short* __restrict__ g1_bf, const unsigned short* __restrict__ cpo_bf,
    const float* __restrict__ bc, const float* __restrict__ bo,
    const int* __restrict__ starts, const int* __restrict__ csr_src, const float* __restrict__ csr_w,
    float* __restrict__ out)
{
    const int lane = threadIdx.x & 63;
    const int node = blockIdx.x * 4 + (threadIdx.x >> 6);
    const int f = lane * 4;
    const int s0 = starts[node];
    const int s1 = starts[node + 1];
    float4 acc = {0.f, 0.f, 0.f, 0.f};
    int i = s0;
    for (; i + 1 < s1; i += 2) {
        int sA = csr_src[i], sB = csr_src[i + 1];
        float wA = csr_w[i], wB = csr_w[i + 1];
        float4 vA = u4tof4(*(const ushort4*)&g1_bf[(size_t)sA * 256 + f]);
        float4 vB = u4tof4(*(const ushort4*)&g1_bf[(size_t)sB * 256 + f]);
        acc.x = fmaf(wA, vA.x, fmaf(wB, vB.x, acc.x));
        acc.y = fmaf(wA, vA.y, fmaf(wB, vB.y, acc.y));
        acc.z = fmaf(wA, vA.z, fmaf(wB, vB.z, acc.z));
        acc.w = fmaf(wA, vA.w, fmaf(wB, vB.w, acc.w));
    }
    if (i < s1) {
        int sA = csr_src[i];
        float wA = csr_w[i];
        float4 vA = u4tof4(*(const ushort4*)&g1_bf[(size_t)sA * 256 + f]);
        acc.x = fmaf(wA, vA.x, acc.x);
        acc.y = fmaf(wA, vA.y, acc.y);
        acc.z = fmaf(wA, vA.z, acc.z);
        acc.w = fmaf(wA, vA.w, acc.w);
    }
    float4 r = u4tof4(*(const ushort4*)&cpo_bf[(size_t)node * 256 + f]);
    float4 b = (f < 128) ? *(const float4*)&bc[f] : *(const float4*)&bo[f - 128];
    r.x += acc.x + b.x; r.y += acc.y + b.y; r.z += acc.z + b.z; r.w += acc.w + b.w;
    if (f < 128) {
        *(float4*)&out[(size_t)node * 128 + f] = r;
    } else {
        r.x = fmaxf(r.x, 0.f); r.y = fmaxf(r.y, 0.f);
        r.z = fmaxf(r.z, 0.f); r.w = fmaxf(r.w, 0.f);
        *(float4*)&out[(size_t)NN * 128 + (size_t)node * 128 + (f - 128)] = r;
    }
}

// ---------------- launch ----------------
extern "C" void kernel_launch(void* const* d_in, const int* in_sizes, int n_in,
                              void* d_out, int out_size, void* d_ws, size_t ws_size,
                              hipStream_t stream)
{
    const float* x   = (const float*)d_in[0];
    const int*   ei  = (const int*)d_in[1];
    const float* ew  = (const float*)d_in[2];
    const float* Wac = (const float*)d_in[3];
    const float* bac = (const float*)d_in[4];
    const float* vac = (const float*)d_in[5];
    const float* Wao = (const float*)d_in[6];
    const float* bao = (const float*)d_in[7];
    const float* vao = (const float*)d_in[8];
    const float* Wc  = (const float*)d_in[9];
    const float* bc  = (const float*)d_in[10];
    const float* Wo  = (const float*)d_in[11];
    const float* bo  = (const float*)d_in[12];
    float* out = (float*)d_out;

    char* ws = (char*)d_ws;
    unsigned short* cpo_bf = (unsigned short*)(ws + 0);         // [N][256] bf16 = 25.6 MB
    unsigned short* g1_bf  = (unsigned short*)(ws + 25600000);  // [N][256] bf16 = 25.6 MB
    short* Bsw1   = (short*)(ws + 51200000);     // 128 KB
    short* Bsw2   = (short*)(ws + 51331072);     // 128 KB
    int*   counts = (int*)(ws + 102400000);
    int*   starts = (int*)(ws + 102600064);
    int*   cursor = (int*)(ws + 102800128);
    int*   csr_src= (int*)(ws + 103000192);
    float* csr_w  = (float*)(ws + 106200192);    // end ~109.4 MB

    const int* src = ei;
    const int* dst = ei + EE;

    hipMemsetAsync(counts, 0, NN * sizeof(int), stream);
    hipMemsetAsync(cursor, 0, NN * sizeof(int), stream);

    k_prew<<<64, 256, 0, stream>>>(Wac, Wao, Wc, Wo, Bsw1, Bsw2);
    k_count<<<(EE + 255) / 256, 256, 0, stream>>>(dst, counts);
    k_scan<<<1, 1024, 0, stream>>>(counts, starts);
    k_fill<<<(EE + 255) / 256, 256, 0, stream>>>(src, dst, ew, starts, cursor, csr_src, csr_w);
    k_att3<<<NN / 8, 256, 0, stream>>>(x, Bsw1, Bsw2, bac, vac, bao, vao, cpo_bf);
    k_hop1<<<NN / 4, 256, 0, stream>>>(cpo_bf, starts, csr_src, csr_w, g1_bf);
    k_hop2<<<NN / 4, 256, 0, stream>>>(g1_bf, cpo_bf, bc, bo, starts, csr_src, csr_w, out);
}